// Round 4
// baseline (256.709 us; speedup 1.0000x reference)
//
#include <hip/hip_runtime.h>
#include <hip/hip_bf16.h>

typedef __bf16 bf16_t;
typedef __bf16 bf16x8 __attribute__((ext_vector_type(8)));
typedef __bf16 bf16x4 __attribute__((ext_vector_type(4)));
typedef float  f32x4  __attribute__((ext_vector_type(4)));

static __device__ __forceinline__ f32x4 mfma16(bf16x8 a, bf16x8 b, f32x4 c) {
    return __builtin_amdgcn_mfma_f32_16x16x32_bf16(a, b, c, 0, 0, 0);
}

// ---------------------------------------------------------------------------
// Pack W1 edge rows [128..160) and W2 [256x256] into bf16 MFMA fragment order:
// frag[(tile16)*64 + lane][j] = W[8*(lane>>4)+j + 32*kstep][ct*16 + (lane&15)]
// ---------------------------------------------------------------------------
__global__ void prep_pack(const float* __restrict__ W1, const float* __restrict__ W2,
                          bf16_t* __restrict__ W1ef, bf16_t* __restrict__ W2f) {
    int t = blockIdx.x * blockDim.x + threadIdx.x;
    int l = t & 63;
    int g = l >> 4;
    int c = l & 15;
    if (t < 1024) {                       // W1 edge part
        int ct = t >> 6;
        #pragma unroll
        for (int j = 0; j < 8; ++j)
            W1ef[t * 8 + j] = (bf16_t)W1[(128 + 8 * g + j) * 256 + ct * 16 + c];
    } else if (t < 1024 + 8192) {         // W2
        int t2 = t - 1024;
        int ks = t2 >> 10;
        int ct = (t2 >> 6) & 15;
        #pragma unroll
        for (int j = 0; j < 8; ++j)
            W2f[t2 * 8 + j] = (bf16_t)W2[(ks * 32 + 8 * g + j) * 256 + ct * 16 + c];
    }
}

// ---------------------------------------------------------------------------
// Pi[b,i,h] = nodes[b,i,:] @ W1[0:128,h] + b1[h]   (f32)
// Pj[b,j,h] = nodes[b,j,:] @ W1[160:288,h]         (f32, temp)
// ---------------------------------------------------------------------------
__global__ __launch_bounds__(256) void prep_pij(const float* __restrict__ nodes,
                                                const float* __restrict__ W1,
                                                const float* __restrict__ b1,
                                                float* __restrict__ Pi,
                                                float* __restrict__ Pj) {
    int b = blockIdx.x >> 2;
    int q = blockIdx.x & 3;
    int h = threadIdx.x;
    const float* nb = nodes + (b * 64 + q * 16) * 128;
    float ai[16], aj[16];
    float bias = b1[h];
    #pragma unroll
    for (int ii = 0; ii < 16; ++ii) { ai[ii] = bias; aj[ii] = 0.f; }
    for (int d = 0; d < 128; ++d) {
        float wi = W1[d * 256 + h];
        float wj = W1[(160 + d) * 256 + h];
        #pragma unroll
        for (int ii = 0; ii < 16; ++ii) {
            float s = nb[ii * 128 + d];
            ai[ii] = fmaf(s, wi, ai[ii]);
            aj[ii] = fmaf(s, wj, aj[ii]);
        }
    }
    #pragma unroll
    for (int ii = 0; ii < 16; ++ii) {
        Pi[(b * 64 + q * 16 + ii) * 256 + h] = ai[ii];
        Pj[(b * 64 + q * 16 + ii) * 256 + h] = aj[ii];
    }
}

// ---------------------------------------------------------------------------
// Repack Pj f32 -> Pjf bf16 fragment-linear per batch (verified layout, R2).
// ---------------------------------------------------------------------------
__global__ __launch_bounds__(256) void prep_pjf(const float* __restrict__ Pj,
                                                bf16_t* __restrict__ Pjf) {
    int u = blockIdx.x * 256 + threadIdx.x;
    int b = u >> 11, u2 = u & 2047;
    int pt = u2 >> 9, ks = (u2 >> 6) & 7, q = (u2 >> 4) & 3, c = u2 & 15;
    int j = pt * 16 + c, h0 = ks * 32 + q * 8;
    const float* src = Pj + ((long)(b * 64 + j)) * 256 + h0;
    f32x4 v0 = *(const f32x4*)src;
    f32x4 v1 = *(const f32x4*)(src + 4);
    bf16x8 o;
    #pragma unroll
    for (int e = 0; e < 4; ++e) { o[e] = (bf16_t)v0[e]; o[4 + e] = (bf16_t)v1[e]; }
    *(bf16x8*)(Pjf + (long)u * 8) = o;
}

// ---------------------------------------------------------------------------
// Persistent fused MLP: 1024 blocks x 8 chunks of 64 pairs, 512 threads.
// L1: 8-way h-split by wave (verified R2/R3 layout; a1f fragment-linear LDS).
// L2: 2 pair-halves (ph) x 4 h-quarters (hq); W2 fragments PINNED in registers
//     (asm keep-alive) -> zero L2$ W2 traffic in steady state; swapped MFMA
//     operands so D=[h][pair] and the L3 dot is in-lane + 2 shfl.
// ---------------------------------------------------------------------------
__global__ __launch_bounds__(512, 2) void mlp_main(
    const float* __restrict__ edges,
    const float* __restrict__ Pi, const bf16_t* __restrict__ Pjf,
    const bf16_t* __restrict__ W1ef, const bf16_t* __restrict__ W2f,
    const float* __restrict__ b2, const float* __restrict__ W3,
    const float* __restrict__ b3, float* __restrict__ out) {

    __shared__ bf16_t a1f[16384];         // 32 KB, single buffer
    __shared__ float part[4][64];         // per-hq partials

    const int p = blockIdx.x;
    const int xb = (p & 7) * 128 + (p >> 3);   // XCD swizzle (1024 % 8 == 0)
    const long cbase = (long)xb * 8;
    const int b = xb >> 3;
    const int tid = threadIdx.x;
    const int w = tid >> 6, l = tid & 63, g = l >> 4, c = l & 15;
    const int ph = w >> 2, hq = w & 3;    // L2 split: pair-half x h-quarter

    // ---- persistent register state ----
    bf16x8 wf[2];                         // W1e frags (L1, h-split by w)
    #pragma unroll
    for (int ht = 0; ht < 2; ++ht)
        wf[ht] = *(const bf16x8*)&W1ef[((w * 2 + ht) * 64 + l) * 8];

    f32x4 w2r[8][4];                      // W2 frags for h-quarter hq: 128 VGPRs
    #pragma unroll
    for (int ks = 0; ks < 8; ++ks)
        #pragma unroll
        for (int ct = 0; ct < 4; ++ct)
            w2r[ks][ct] = *(const f32x4*)&W2f[((ks * 16 + hq * 4 + ct) * 64 + l) * 8];
    #pragma unroll
    for (int ks = 0; ks < 8; ++ks)
        #pragma unroll
        for (int ct = 0; ct < 4; ++ct)
            asm volatile("" : "+v"(w2r[ks][ct]));   // forbid remat: keep resident

    int offA[4][2];
    bf16x4 pj[4][2];                      // Pjf depends only on b -> hoist
    {
        const bf16_t* PjB = Pjf + (long)b * 16384;
        #pragma unroll
        for (int pt = 0; pt < 4; ++pt)
            #pragma unroll
            for (int ht = 0; ht < 2; ++ht) {
                int U = (pt * 8 + w) * 64 + (2 * ht + (g >> 1)) * 16 + c;
                offA[pt][ht] = U * 8 + 4 * (g & 1);
                pj[pt][ht] = *(const bf16x4*)(PjB + offA[pt][ht]);
            }
    }

    const float bias3 = b3[0];
    const float* ebase = edges + cbase * 2048 + (long)c * 32 + 8 * g;

    f32x4 e0[4], e1[4], piv[2];
    // prologue loads for chunk 0
    #pragma unroll
    for (int pt = 0; pt < 4; ++pt) {
        e0[pt] = *(const f32x4*)(ebase + pt * 512);
        e1[pt] = *(const f32x4*)(ebase + pt * 512 + 4);
    }
    {
        const float* pp = Pi + cbase * 256 + w * 32 + 4 * g;
        piv[0] = *(const f32x4*)pp;
        piv[1] = *(const f32x4*)(pp + 16);
    }

    for (int t = 0; t < 8; ++t) {
        // deferred out-write for chunk t-1 (part stable until L2(t) after bar1)
        if (t > 0 && tid < 64) {
            float s = bias3;
            #pragma unroll
            for (int hh = 0; hh < 4; ++hh) s += part[hh][tid];
            out[(cbase + t - 1) * 64 + tid] = s;
        }

        // ---------------- layer 1 (uses e/piv regs of chunk t) ----------------
        {
            const f32x4 z4 = {0.f, 0.f, 0.f, 0.f};
            f32x4 acc1[2][4];
            #pragma unroll
            for (int ht = 0; ht < 2; ++ht)
                #pragma unroll
                for (int pt = 0; pt < 4; ++pt) acc1[ht][pt] = z4;
            bf16x8 ef[4];
            #pragma unroll
            for (int pt = 0; pt < 4; ++pt)
                #pragma unroll
                for (int j2 = 0; j2 < 4; ++j2) {
                    ef[pt][j2]     = (bf16_t)e0[pt][j2];
                    ef[pt][4 + j2] = (bf16_t)e1[pt][j2];
                }
            #pragma unroll
            for (int pt = 0; pt < 4; ++pt)
                #pragma unroll
                for (int ht = 0; ht < 2; ++ht)
                    acc1[ht][pt] = mfma16(wf[ht], ef[pt], acc1[ht][pt]);
            #pragma unroll
            for (int pt = 0; pt < 4; ++pt)
                #pragma unroll
                for (int ht = 0; ht < 2; ++ht) {
                    bf16x4 o;
                    #pragma unroll
                    for (int r = 0; r < 4; ++r) {
                        float v = acc1[ht][pt][r] + piv[ht][r] + (float)pj[pt][ht][r];
                        v = v > 0.f ? v : 0.f;
                        o[r] = (bf16_t)v;
                    }
                    *(bf16x4*)(&a1f[offA[pt][ht]]) = o;
                }
        }
        __syncthreads();                  // bar1: a1f ready

        // prefetch chunk t+1 (in flight across the whole L2 phase)
        if (t < 7) {
            const float* ep = ebase + (long)(t + 1) * 2048;
            #pragma unroll
            for (int pt = 0; pt < 4; ++pt) {
                e0[pt] = *(const f32x4*)(ep + pt * 512);
                e1[pt] = *(const f32x4*)(ep + pt * 512 + 4);
            }
            const float* pp = Pi + (cbase + t + 1) * 256 + w * 32 + 4 * g;
            piv[0] = *(const f32x4*)pp;
            piv[1] = *(const f32x4*)(pp + 16);
        }

        // ---------------- layer 2 (swapped: A=W2 frag, B=a1 frag) -------------
        {
            const f32x4 z4 = {0.f, 0.f, 0.f, 0.f};
            f32x4 acc2[4][2];             // [ct][rtl] : D[h][pair]
            #pragma unroll
            for (int ct = 0; ct < 4; ++ct)
                #pragma unroll
                for (int rtl = 0; rtl < 2; ++rtl) acc2[ct][rtl] = z4;
            #pragma unroll
            for (int ks = 0; ks < 8; ++ks) {
                bf16x8 af[2];
                #pragma unroll
                for (int rtl = 0; rtl < 2; ++rtl)
                    af[rtl] = *(const bf16x8*)&a1f[(((ph * 2 + rtl) * 8 + ks) * 64 + l) * 8];
                #pragma unroll
                for (int ct = 0; ct < 4; ++ct)
                    #pragma unroll
                    for (int rtl = 0; rtl < 2; ++rtl)
                        acc2[ct][rtl] = mfma16(*(const bf16x8*)&w2r[ks][ct], af[rtl],
                                               acc2[ct][rtl]);
            }

            // L3 epilogue: h = hq*64 + ct*16 + 4g + r (in-lane), pair = (ph*2+rtl)*16 + c
            f32x4 b2q[4], w3q[4];
            #pragma unroll
            for (int ct = 0; ct < 4; ++ct) {
                b2q[ct] = *(const f32x4*)&b2[hq * 64 + ct * 16 + 4 * g];
                w3q[ct] = *(const f32x4*)&W3[hq * 64 + ct * 16 + 4 * g];
            }
            #pragma unroll
            for (int rtl = 0; rtl < 2; ++rtl) {
                float s = 0.f;
                #pragma unroll
                for (int ct = 0; ct < 4; ++ct)
                    #pragma unroll
                    for (int r = 0; r < 4; ++r) {
                        float v = acc2[ct][rtl][r] + b2q[ct][r];
                        v = v > 0.f ? v : 0.f;
                        s = fmaf(v, w3q[ct][r], s);
                    }
                s += __shfl_xor(s, 16);   // reduce over g (2 steps, not 4)
                s += __shfl_xor(s, 32);
                if (g == 0) part[hq][(ph * 2 + rtl) * 16 + c] = s;
            }
        }
        __syncthreads();                  // bar2: part ready, a1f free
    }

    // out for chunk 7
    if (tid < 64) {
        float s = bias3;
        #pragma unroll
        for (int hh = 0; hh < 4; ++hh) s += part[hh][tid];
        out[(cbase + 7) * 64 + tid] = s;
    }
}

extern "C" void kernel_launch(void* const* d_in, const int* in_sizes, int n_in,
                              void* d_out, int out_size, void* d_ws, size_t ws_size,
                              hipStream_t stream) {
    const float* nodes = (const float*)d_in[0];
    const float* edges = (const float*)d_in[1];
    const float* W1    = (const float*)d_in[2];
    const float* b1    = (const float*)d_in[3];
    const float* W2    = (const float*)d_in[4];
    const float* b2    = (const float*)d_in[5];
    const float* W3    = (const float*)d_in[6];
    const float* b3    = (const float*)d_in[7];
    float* out = (float*)d_out;

    char* ws = (char*)d_ws;
    float*  Pi   = (float*)ws;                                        // 8 MB
    float*  Pj   = (float*)(ws + (size_t)8 * 1024 * 1024);            // 8 MB (temp)
    bf16_t* Pjf  = (bf16_t*)(ws + (size_t)16 * 1024 * 1024);          // 4 MB
    bf16_t* W2f  = (bf16_t*)(ws + (size_t)20 * 1024 * 1024);          // 128 KB
    bf16_t* W1ef = (bf16_t*)(ws + (size_t)20 * 1024 * 1024 + 131072); // 16 KB

    prep_pack<<<dim3(36), dim3(256), 0, stream>>>(W1, W2, W1ef, W2f);
    prep_pij<<<dim3(512), dim3(256), 0, stream>>>(nodes, W1, b1, Pi, Pj);
    prep_pjf<<<dim3(1024), dim3(256), 0, stream>>>(Pj, Pjf);
    mlp_main<<<dim3(1024), dim3(512), 0, stream>>>(edges, Pi, Pjf, W1ef, W2f, b2, W3, b3, out);
}